// Round 2
// baseline (221.169 us; speedup 1.0000x reference)
//
#include <hip/hip_runtime.h>

#define ALPHA_LEAKY 0.2f
#define EPS_F 1e-10f

#define BSHIFT 7            // bucket = 128 qi
#define BRANGE 128
#define NBMAX 1024          // max buckets (Nq <= 131072)
#define CHUNK 16384         // edges per bin_kernel block
#define KBUF_CAP 3072       // bucket LDS capacity (avg 2048, +22 sigma)
#define HIST_BLOCKS 512

__device__ __forceinline__ float readlane_f(float v, int lane) {
  return __int_as_float(__builtin_amdgcn_readlane(__float_as_int(v), lane));
}

// RNE float -> bf16
__device__ __forceinline__ unsigned short f2bf(float x) {
  unsigned int u = __float_as_uint(x);
  return (unsigned short)((u + 0x7fffu + ((u >> 16) & 1u)) >> 16);
}

// Pin a float4's components into VGPRs: asm results are opaque -> the
// register allocator cannot rematerialize (re-load) them inside the loop.
#define PIN4(v) asm volatile("" : "+v"(v.x), "+v"(v.y), "+v"(v.z), "+v"(v.w))

// ---------------------------------------------------------------------------
// hist_proj_kernel: two independent jobs in one launch (blockIdx split).
//  blocks [0, HIST_BLOCKS): LDS histogram of qi>>BSHIFT -> gcnt
//  blocks [HIST_BLOCKS, +projBlocks): fold + q-gemv + kv projection
// kv projection holds W row in 16 float4 VGPRs. Round-1 evidence: without
// __launch_bounds__(.,2) + asm pinning, LLVM's RA targets 8-wave occupancy
// (VGPR_Count=44) and REMATERIALIZES the W loads inside the loop -> ~6MB/CU
// of L1 traffic per dispatch -> 66us. The pin forces them resident.
// ---------------------------------------------------------------------------
__global__ __launch_bounds__(256, 2) void hist_proj_kernel(
    const int* __restrict__ eq, int* __restrict__ gcnt, int E, int NB,
    const float* __restrict__ qnodes, const float* __restrict__ kvnodes,
    const float* __restrict__ W, const float* __restrict__ pb,
    const float* __restrict__ aw, unsigned int* __restrict__ Kp16,
    float* __restrict__ sq, float* __restrict__ sk,
    int Nq, int Nk, int projBlocks) {
  const int t = threadIdx.x;
  if (blockIdx.x < HIST_BLOCKS) {
    // ---- histogram ----
    __shared__ int lcnt[NBMAX];
    for (int i = t; i < NBMAX; i += 256) lcnt[i] = 0;
    __syncthreads();
    const int n4 = E >> 2;
    for (int i = blockIdx.x * 256 + t; i < n4; i += HIST_BLOCKS * 256) {
      const int4 q = ((const int4*)eq)[i];
      atomicAdd(&lcnt[q.x >> BSHIFT], 1);
      atomicAdd(&lcnt[q.y >> BSHIFT], 1);
      atomicAdd(&lcnt[q.z >> BSHIFT], 1);
      atomicAdd(&lcnt[q.w >> BSHIFT], 1);
    }
    if (blockIdx.x == 0 && t < (E & 3))
      atomicAdd(&lcnt[eq[(n4 << 2) + t] >> BSHIFT], 1);
    __syncthreads();
    for (int i = t; i < NB; i += 256)
      if (lcnt[i]) atomicAdd(&gcnt[i], lcnt[i]);
    return;
  }

  // ---- projections ----
  __shared__ float us[64];
  __shared__ float cq_s;
  const int bid = blockIdx.x - HIST_BLOCKS;

  const int lane = t & 63;
  const int waveId = bid * 4 + (t >> 6);
  const int nWaves = projBlocks * 4;

  // fold: u_q, c_q (first 64 threads; W read straight from global, coalesced)
  if (t < 64) {
    float s = 0.f;
#pragma unroll 8
    for (int o = 0; o < 64; ++o) s = fmaf(aw[o], W[o * 64 + t], s);
    us[t] = s;
    if (t == 0) {
      float c = 0.f;
      for (int o = 0; o < 64; ++o) c = fmaf(aw[o], pb[o], c);
      cq_s = c;
    }
  }
  __syncthreads();

  // q-side gemv: sq[n] = qnodes[n,:].u_q + c_q (4 nodes per wave-iter)
  {
    const int sub = lane & 15, ng = lane >> 4;
    const float4 uv = ((const float4*)us)[sub];
    const float c = cq_s;
    for (int base = waveId * 4; base < Nq; base += nWaves * 4) {
      const int n = base + ng;
      float s = 0.f;
      if (n < Nq) {
        const float4 x = *(const float4*)(qnodes + (size_t)n * 64 + sub * 4);
        s = x.x * uv.x + x.y * uv.y + x.z * uv.z + x.w * uv.w;
      }
#pragma unroll
      for (int off = 1; off <= 8; off <<= 1) s += __shfl_xor(s, off, 64);
      if (sub == 0 && n < Nq) sq[n] = s + c;
    }
  }

  // kv projection: Kp16 bf16-packed + folded sk dot.
  // W row of this lane's output dim held in 16 PINNED float4 registers.
  const float4* Wr = (const float4*)(W + (size_t)lane * 64);
  float4 w0 = Wr[0], w1 = Wr[1], w2 = Wr[2], w3 = Wr[3];
  float4 w4 = Wr[4], w5 = Wr[5], w6 = Wr[6], w7 = Wr[7];
  float4 w8 = Wr[8], w9 = Wr[9], w10 = Wr[10], w11 = Wr[11];
  float4 w12 = Wr[12], w13 = Wr[13], w14 = Wr[14], w15 = Wr[15];
  PIN4(w0); PIN4(w1); PIN4(w2); PIN4(w3);
  PIN4(w4); PIN4(w5); PIN4(w6); PIN4(w7);
  PIN4(w8); PIN4(w9); PIN4(w10); PIN4(w11);
  PIN4(w12); PIN4(w13); PIN4(w14); PIN4(w15);
  const float bl = pb[lane];
  const float avl = aw[64 + lane];

  int n = waveId;
  if (n < Nk) {
    float xv = kvnodes[(size_t)n * 64 + lane];
    while (n < Nk) {
      const int nn = n + nWaves;
      float xn = 0.f;
      if (nn < Nk) xn = kvnodes[(size_t)nn * 64 + lane];  // prefetch next node

      // 4 interleaved accumulator chains (16-deep each), readlane broadcasts
      float a0 = bl, a1 = 0.f, a2 = 0.f, a3 = 0.f;
#define KSTEP(Q, WV)                                   \
  a0 = fmaf(readlane_f(xv, 4 * Q + 0), WV.x, a0);      \
  a1 = fmaf(readlane_f(xv, 4 * Q + 1), WV.y, a1);      \
  a2 = fmaf(readlane_f(xv, 4 * Q + 2), WV.z, a2);      \
  a3 = fmaf(readlane_f(xv, 4 * Q + 3), WV.w, a3);
      KSTEP(0, w0) KSTEP(1, w1) KSTEP(2, w2) KSTEP(3, w3)
      KSTEP(4, w4) KSTEP(5, w5) KSTEP(6, w6) KSTEP(7, w7)
      KSTEP(8, w8) KSTEP(9, w9) KSTEP(10, w10) KSTEP(11, w11)
      KSTEP(12, w12) KSTEP(13, w13) KSTEP(14, w14) KSTEP(15, w15)
#undef KSTEP
      const float acc = (a0 + a1) + (a2 + a3);

      const float nb = __shfl_xor(acc, 1, 64);
      if (!(lane & 1))
        Kp16[(size_t)n * 32 + (lane >> 1)] =
            ((unsigned int)f2bf(nb) << 16) | f2bf(acc);
      float ws = acc * avl;
#pragma unroll
      for (int off = 32; off > 0; off >>= 1) ws += __shfl_xor(ws, off, 64);
      if (lane == 0) sk[n] = ws;

      xv = xn;
      n = nn;
    }
  }
}

// ---------------------------------------------------------------------------
// bucket_scan: exclusive scan of gcnt[0..NB) -> gbase, gcursor. NB <= 1024.
// ---------------------------------------------------------------------------
__global__ __launch_bounds__(1024) void bucket_scan(
    const int* __restrict__ gcnt, int* __restrict__ gbase,
    int* __restrict__ gcursor, int NB) {
  __shared__ int wso[16];
  const int t = threadIdx.x, lane = t & 63, wv = t >> 6;
  const int v = (t < NB) ? gcnt[t] : 0;
  int x = v;
#pragma unroll
  for (int off = 1; off < 64; off <<= 1) {
    const int y = __shfl_up(x, off, 64);
    if (lane >= off) x += y;
  }
  if (lane == 63) wso[wv] = x;
  __syncthreads();
  int woff = 0;
  for (int w = 0; w < wv; ++w) woff += wso[w];
  const int excl = woff + x - v;
  if (t < NB) { gbase[t] = excl; gcursor[t] = excl; }
}

// ---------------------------------------------------------------------------
// bin_kernel: 1024 threads, 16384 edges/block: coalesced int4 reads into
// registers, LDS per-bucket count, ONE reservation atomic per bucket per
// block, (qi,ki) pairs written in ~168B contiguous runs.
// ---------------------------------------------------------------------------
__global__ __launch_bounds__(1024) void bin_kernel(
    const int* __restrict__ eq, const int* __restrict__ ek,
    int* __restrict__ gcursor, int2* __restrict__ pairs, int E, int NB) {
  __shared__ int lcnt[NBMAX];
  __shared__ int lbase[NBMAX];
  const int t = threadIdx.x;
  for (int i = t; i < NBMAX; i += 1024) lcnt[i] = 0;
  __syncthreads();

  const int cbase = blockIdx.x * CHUNK;
  int4 qv[4], kv[4];
#pragma unroll
  for (int j = 0; j < 4; ++j) {
    const int e0 = cbase + (((j << 10) + t) << 2);
    if (e0 + 3 < E) {
      qv[j] = *(const int4*)(eq + e0);
      kv[j] = *(const int4*)(ek + e0);
    } else {
      int tq[4] = {-1, -1, -1, -1}, tk[4] = {0, 0, 0, 0};
      for (int r = 0; r < 4; ++r)
        if (e0 + r < E) { tq[r] = eq[e0 + r]; tk[r] = ek[e0 + r]; }
      qv[j] = make_int4(tq[0], tq[1], tq[2], tq[3]);
      kv[j] = make_int4(tk[0], tk[1], tk[2], tk[3]);
    }
    if (qv[j].x >= 0) atomicAdd(&lcnt[qv[j].x >> BSHIFT], 1);
    if (qv[j].y >= 0) atomicAdd(&lcnt[qv[j].y >> BSHIFT], 1);
    if (qv[j].z >= 0) atomicAdd(&lcnt[qv[j].z >> BSHIFT], 1);
    if (qv[j].w >= 0) atomicAdd(&lcnt[qv[j].w >> BSHIFT], 1);
  }
  __syncthreads();
  for (int i = t; i < NB; i += 1024) {
    lbase[i] = lcnt[i] ? atomicAdd(&gcursor[i], lcnt[i]) : 0;
    lcnt[i] = 0;
  }
  __syncthreads();
#pragma unroll
  for (int j = 0; j < 4; ++j) {
    const int qs[4] = {qv[j].x, qv[j].y, qv[j].z, qv[j].w};
    const int ks[4] = {kv[j].x, kv[j].y, kv[j].z, kv[j].w};
#pragma unroll
    for (int r = 0; r < 4; ++r) {
      if (qs[r] >= 0) {
        const int b = qs[r] >> BSHIFT;
        pairs[lbase[b] + atomicAdd(&lcnt[b], 1)] = make_int2(qs[r], ks[r]);
      }
    }
  }
}

// ---------------------------------------------------------------------------
// sort_agg_kernel: one 512-thr block per 128-qi bucket (782 blocks ~3/CU).
// Phase A: register-cache the bucket's pairs, LDS counting-sort ki -> kibuf.
// Phase B (TRANSPOSED): lane = (node-sub ng 0..7, dim-group dg 0..7); each
// lane owns 8 dims of one node and walks that node's full edge list (2x
// unrolled). NO cross-lane reduction, no edge-slot padding: wsum is computed
// redundantly by the node's 8 lanes; each lane stores its own 32B directly
// (256B contiguous per node across its 8 lanes).
// ---------------------------------------------------------------------------
__global__ __launch_bounds__(512, 6) void sort_agg_kernel(
    const int2* __restrict__ pairs, const int* __restrict__ gcnt,
    const int* __restrict__ gbase, const float* __restrict__ sq,
    const float* __restrict__ sk, const float* __restrict__ ab,
    const unsigned int* __restrict__ Kp16, float* __restrict__ out,
    int Nq) {
  __shared__ int lcnt[BRANGE];
  __shared__ int lcur[BRANGE];
  __shared__ int lstart[BRANGE + 1];
  __shared__ int kibuf[KBUF_CAP];
  __shared__ int wso2[2];

  const int t = threadIdx.x;
  const int b = blockIdx.x;
  const int qlo = b << BSHIFT;
  int n = gcnt[b];
  if (n > KBUF_CAP) n = KBUF_CAP;  // statistically never; OOB guard
  const int base = gbase[b];

  if (t < BRANGE) lcnt[t] = 0;
  __syncthreads();

  // cache this thread's pairs (<= 6 at KBUF_CAP 3072)
  int2 pv[6];
  int np = 0;
#pragma unroll
  for (int r = 0; r < 6; ++r) {
    const int i = t + (r << 9);
    if (i < n) { pv[r] = pairs[base + i]; ++np; }
  }
#pragma unroll
  for (int r = 0; r < 6; ++r)
    if (r < np) atomicAdd(&lcnt[pv[r].x - qlo], 1);
  __syncthreads();

  // exclusive scan of lcnt[0..127] (first 2 waves)
  const int lane = t & 63, wv = t >> 6;
  int v = 0, x = 0;
  if (t < BRANGE) {
    v = lcnt[t];
    x = v;
#pragma unroll
    for (int off = 1; off < 64; off <<= 1) {
      const int y = __shfl_up(x, off, 64);
      if (lane >= off) x += y;
    }
    if (lane == 63) wso2[wv] = x;
  }
  __syncthreads();
  if (t < BRANGE) {
    const int excl = ((wv == 1) ? wso2[0] : 0) + x - v;
    lstart[t] = excl;
    lcur[t] = excl;
    if (t == BRANGE - 1) lstart[BRANGE] = excl + v;
  }
  __syncthreads();

  // scatter ki into kibuf (sorted by local qi)
#pragma unroll
  for (int r = 0; r < 6; ++r)
    if (r < np) kibuf[atomicAdd(&lcur[pv[r].x - qlo], 1)] = pv[r].y;
  __syncthreads();

  // Phase B: transposed aggregation. 8 waves x 8 nodes = 64 nodes per pass.
  const int ng = lane >> 3, dg = lane & 7;
  const float abv = ab[0];
#pragma unroll
  for (int pass = 0; pass < 2; ++pass) {
    const int l = (pass << 6) + (wv << 3) + ng;
    const int node = qlo + l;
    const bool act = node < Nq;
    const int s = act ? lstart[l] : 0;
    const int e = act ? lstart[l + 1] : 0;
    const float sqn = act ? sq[node] + abv : 0.f;

    float acc[8] = {0.f, 0.f, 0.f, 0.f, 0.f, 0.f, 0.f, 0.f};
    float wsum = 0.f;
    int j = s;
    for (; j + 1 < e; j += 2) {
      const int k1 = kibuf[j];
      const int k2 = kibuf[j + 1];
      float x1 = sqn + sk[k1];
      float x2 = sqn + sk[k2];
      x1 = x1 > 0.f ? x1 : ALPHA_LEAKY * x1;
      x2 = x2 > 0.f ? x2 : ALPHA_LEAKY * x2;
      const float w1 = __expf(x1);
      const float w2 = __expf(x2);
      const uint4 u1 = *(const uint4*)(Kp16 + (size_t)k1 * 32 + (dg << 2));
      const uint4 u2 = *(const uint4*)(Kp16 + (size_t)k2 * 32 + (dg << 2));
      acc[0] = fmaf(w1, __uint_as_float(u1.x << 16), acc[0]);
      acc[1] = fmaf(w1, __uint_as_float(u1.x & 0xffff0000u), acc[1]);
      acc[2] = fmaf(w1, __uint_as_float(u1.y << 16), acc[2]);
      acc[3] = fmaf(w1, __uint_as_float(u1.y & 0xffff0000u), acc[3]);
      acc[4] = fmaf(w1, __uint_as_float(u1.z << 16), acc[4]);
      acc[5] = fmaf(w1, __uint_as_float(u1.z & 0xffff0000u), acc[5]);
      acc[6] = fmaf(w1, __uint_as_float(u1.w << 16), acc[6]);
      acc[7] = fmaf(w1, __uint_as_float(u1.w & 0xffff0000u), acc[7]);
      acc[0] = fmaf(w2, __uint_as_float(u2.x << 16), acc[0]);
      acc[1] = fmaf(w2, __uint_as_float(u2.x & 0xffff0000u), acc[1]);
      acc[2] = fmaf(w2, __uint_as_float(u2.y << 16), acc[2]);
      acc[3] = fmaf(w2, __uint_as_float(u2.y & 0xffff0000u), acc[3]);
      acc[4] = fmaf(w2, __uint_as_float(u2.z << 16), acc[4]);
      acc[5] = fmaf(w2, __uint_as_float(u2.z & 0xffff0000u), acc[5]);
      acc[6] = fmaf(w2, __uint_as_float(u2.w << 16), acc[6]);
      acc[7] = fmaf(w2, __uint_as_float(u2.w & 0xffff0000u), acc[7]);
      wsum += w1 + w2;
    }
    if (j < e) {
      const int k1 = kibuf[j];
      float x1 = sqn + sk[k1];
      x1 = x1 > 0.f ? x1 : ALPHA_LEAKY * x1;
      const float w1 = __expf(x1);
      const uint4 u1 = *(const uint4*)(Kp16 + (size_t)k1 * 32 + (dg << 2));
      acc[0] = fmaf(w1, __uint_as_float(u1.x << 16), acc[0]);
      acc[1] = fmaf(w1, __uint_as_float(u1.x & 0xffff0000u), acc[1]);
      acc[2] = fmaf(w1, __uint_as_float(u1.y << 16), acc[2]);
      acc[3] = fmaf(w1, __uint_as_float(u1.y & 0xffff0000u), acc[3]);
      acc[4] = fmaf(w1, __uint_as_float(u1.z << 16), acc[4]);
      acc[5] = fmaf(w1, __uint_as_float(u1.z & 0xffff0000u), acc[5]);
      acc[6] = fmaf(w1, __uint_as_float(u1.w << 16), acc[6]);
      acc[7] = fmaf(w1, __uint_as_float(u1.w & 0xffff0000u), acc[7]);
      wsum += w1;
    }
    if (act) {
      const float inv = 1.0f / (wsum + EPS_F);
      float4 r0 = {acc[0] * inv, acc[1] * inv, acc[2] * inv, acc[3] * inv};
      float4 r1 = {acc[4] * inv, acc[5] * inv, acc[6] * inv, acc[7] * inv};
      float* o = out + (size_t)node * 64 + (dg << 3);
      *(float4*)o = r0;
      *(float4*)(o + 4) = r1;
    }
  }
}

extern "C" void kernel_launch(void* const* d_in, const int* in_sizes, int n_in,
                              void* d_out, int out_size, void* d_ws, size_t ws_size,
                              hipStream_t stream) {
  const float* qnodes = (const float*)d_in[0];   // (Nq, 64) f32
  const float* kvnodes = (const float*)d_in[1];  // (Nk, 64) f32
  const int* ei = (const int*)d_in[2];           // (2, E) int32
  const float* W = (const float*)d_in[3];        // (64, 64)
  const float* pb = (const float*)d_in[4];       // (64,)
  const float* aw = (const float*)d_in[5];       // (1, 128): [wq | wk]
  const float* ab = (const float*)d_in[6];       // (1,)

  const int Nq = in_sizes[0] / 64;
  const int Nk = in_sizes[1] / 64;
  const int E = in_sizes[2] / 2;
  const int NB = (Nq + BRANGE - 1) >> BSHIFT;    // 782 at Nq=100000

  const int* eq = ei;
  const int* ek = ei + E;

  // --- workspace layout ---
  char* ws = (char*)d_ws;
  int2* pairs = (int2*)ws;                              // E int2
  unsigned int* Kp16 = (unsigned int*)(pairs + E);      // Nk*32 words
  float* sq = (float*)(Kp16 + (size_t)Nk * 32);         // Nq
  float* sk = sq + Nq;                                  // Nk
  int* gcnt = (int*)(sk + Nk);                          // NBMAX
  int* gbase = gcnt + NBMAX;                            // NBMAX
  int* gcursor = gbase + NBMAX;                         // NBMAX

  hipMemsetAsync(gcnt, 0, NBMAX * sizeof(int), stream);

  // --- hist + projections (independent; fused into one launch) ---
  const int projBlocks = 1536;
  hist_proj_kernel<<<HIST_BLOCKS + projBlocks, 256, 0, stream>>>(
      eq, gcnt, E, NB, qnodes, kvnodes, W, pb, aw, Kp16, sq, sk, Nq, Nk,
      projBlocks);

  // --- scan + binning ---
  bucket_scan<<<1, 1024, 0, stream>>>(gcnt, gbase, gcursor, NB);
  bin_kernel<<<(E + CHUNK - 1) / CHUNK, 1024, 0, stream>>>(eq, ek, gcursor,
                                                           pairs, E, NB);

  // --- fused bucket sort + transposed aggregation ---
  sort_agg_kernel<<<NB, 512, 0, stream>>>(pairs, gcnt, gbase, sq, sk, ab,
                                          Kp16, (float*)d_out, Nq);
}

// Round 3
// 213.780 us; speedup vs baseline: 1.0346x; 1.0346x over previous
//
#include <hip/hip_runtime.h>

#define ALPHA_LEAKY 0.2f
#define EPS_F 1e-10f

#define BSHIFT 7            // bucket = 128 qi
#define BRANGE 128
#define NBMAX 1024          // max buckets (Nq <= 131072)
#define CHUNK 16384         // edges per bin_kernel block
#define KBUF_CAP 3072       // bucket LDS capacity (avg 2048, +22 sigma)
#define HIST_BLOCKS 128     // 128*782 = 100k global atomics (was 400k)
#define WLD 68              // W LDS row stride (dwords): 16B-aligned, even banks

__device__ __forceinline__ float readlane_f(float v, int lane) {
  return __int_as_float(__builtin_amdgcn_readlane(__float_as_int(v), lane));
}

// RNE float -> bf16
__device__ __forceinline__ unsigned short f2bf(float x) {
  unsigned int u = __float_as_uint(x);
  return (unsigned short)((u + 0x7fffu + ((u >> 16) & 1u)) >> 16);
}

// ---------------------------------------------------------------------------
// hist_proj_kernel: two independent jobs in one launch (blockIdx split).
//  blocks [0, HIST_BLOCKS): LDS histogram of qi>>BSHIFT -> gcnt
//  blocks [HIST_BLOCKS, +projBlocks): fold + q/k gemv + kv projection
//
// kv-projection history: rounds 0-2 tried to keep each lane's 64-float W row
// resident (LDS re-read / L1 remat / scratch spill) -- all ~63-70us because
// all re-fetch 256B of W per lane per node. This version needs only 4 W VGPRs
// live: W staged in LDS [64][WLD], read as ONE ds_read_b128 per 4-dim chunk,
// amortized over 8 nodes -> 2 b128/node instead of 64 b32/node (32x less LDS
// pipe traffic). sk is FOLDED (sk = x.uk + ck, uk = W^T aw_k) like the q side,
// removing the per-node 6-shfl reduction from the hot loop.
// ---------------------------------------------------------------------------
__global__ __launch_bounds__(256) void hist_proj_kernel(
    const int* __restrict__ eq, int* __restrict__ gcnt, int E, int NB,
    const float* __restrict__ qnodes, const float* __restrict__ kvnodes,
    const float* __restrict__ W, const float* __restrict__ pb,
    const float* __restrict__ aw, unsigned int* __restrict__ Kp16,
    float* __restrict__ sq, float* __restrict__ sk,
    int Nq, int Nk, int projBlocks) {
  const int t = threadIdx.x;
  if (blockIdx.x < HIST_BLOCKS) {
    // ---- histogram ----
    __shared__ int lcnt[NBMAX];
    for (int i = t; i < NBMAX; i += 256) lcnt[i] = 0;
    __syncthreads();
    const int n4 = E >> 2;
    for (int i = blockIdx.x * 256 + t; i < n4; i += HIST_BLOCKS * 256) {
      const int4 q = ((const int4*)eq)[i];
      atomicAdd(&lcnt[q.x >> BSHIFT], 1);
      atomicAdd(&lcnt[q.y >> BSHIFT], 1);
      atomicAdd(&lcnt[q.z >> BSHIFT], 1);
      atomicAdd(&lcnt[q.w >> BSHIFT], 1);
    }
    if (blockIdx.x == 0 && t < (E & 3))
      atomicAdd(&lcnt[eq[(n4 << 2) + t] >> BSHIFT], 1);
    __syncthreads();
    for (int i = t; i < NB; i += 256)
      if (lcnt[i]) atomicAdd(&gcnt[i], lcnt[i]);
    return;
  }

  // ---- projections ----
  __shared__ __align__(16) float Ws[64 * WLD];
  __shared__ float pt0[256];
  __shared__ float pt1[256];
  __shared__ __align__(16) float us[64];
  __shared__ __align__(16) float uk[64];
  __shared__ float cq_s, ck_s;
  const int bid = blockIdx.x - HIST_BLOCKS;
  const int lane = t & 63;
  const int waveId = bid * 4 + (t >> 6);
  const int nWaves = projBlocks * 4;

  // stage W -> LDS [64][WLD]
  for (int i = t; i < 4096; i += 256) Ws[(i >> 6) * WLD + (i & 63)] = W[i];
  __syncthreads();

  // fold: us = W^T aw_q, uk = W^T aw_k (256-thread partial sums, 16 o's each)
  {
    const int pd = t & 63, og = t >> 6;
    float s0 = 0.f, s1 = 0.f;
#pragma unroll
    for (int oo = 0; oo < 16; ++oo) {
      const int o = og * 16 + oo;
      const float wv = Ws[o * WLD + pd];
      s0 = fmaf(aw[o], wv, s0);
      s1 = fmaf(aw[64 + o], wv, s1);
    }
    pt0[t] = s0;
    pt1[t] = s1;
  }
  __syncthreads();
  if (t < 64) {
    us[t] = (pt0[t] + pt0[t + 64]) + (pt0[t + 128] + pt0[t + 192]);
    uk[t] = (pt1[t] + pt1[t + 64]) + (pt1[t + 128] + pt1[t + 192]);
    if (t == 0) {
      float c0 = 0.f, c1 = 0.f;
      for (int o = 0; o < 64; ++o) {
        c0 = fmaf(aw[o], pb[o], c0);
        c1 = fmaf(aw[64 + o], pb[o], c1);
      }
      cq_s = c0;
      ck_s = c1;
    }
  }
  __syncthreads();

  // q-side gemv: sq[n] = qnodes[n,:].us + cq (4 nodes per wave-iter)
  {
    const int sub = lane & 15, ng = lane >> 4;
    const float4 uv = ((const float4*)us)[sub];
    const float c = cq_s;
    for (int base = waveId * 4; base < Nq; base += nWaves * 4) {
      const int n = base + ng;
      float s = 0.f;
      if (n < Nq) {
        const float4 x = *(const float4*)(qnodes + (size_t)n * 64 + sub * 4);
        s = x.x * uv.x + x.y * uv.y + x.z * uv.z + x.w * uv.w;
      }
#pragma unroll
      for (int off = 1; off <= 8; off <<= 1) s += __shfl_xor(s, off, 64);
      if (sub == 0 && n < Nq) sq[n] = s + c;
    }
  }

  // k-side folded gemv: sk[n] = kvnodes[n,:].uk + ck
  {
    const int sub = lane & 15, ng = lane >> 4;
    const float4 uv = ((const float4*)uk)[sub];
    const float c = ck_s;
    for (int base = waveId * 4; base < Nk; base += nWaves * 4) {
      const int n = base + ng;
      float s = 0.f;
      if (n < Nk) {
        const float4 x = *(const float4*)(kvnodes + (size_t)n * 64 + sub * 4);
        s = x.x * uv.x + x.y * uv.y + x.z * uv.z + x.w * uv.w;
      }
#pragma unroll
      for (int off = 1; off <= 8; off <<= 1) s += __shfl_xor(s, off, 64);
      if (sub == 0 && n < Nk) sk[n] = s + c;
    }
  }

  // kv projection: 8 nodes per wave-iteration. lane = output dim o.
  // Per 4-dim chunk: 1 ds_read_b128 of W[o][4c..4c+3], x broadcast via
  // readlane (compile-time lane index after full unroll).
  const float bl = pb[lane];
  const int ngroups = (Nk + 7) >> 3;
  for (int g = waveId; g < ngroups; g += nWaves) {
    const int n0 = g << 3;
    const float* xb = kvnodes + (size_t)n0 * 64 + lane;
    const float x0 = (n0 + 0 < Nk) ? xb[0 * 64] : 0.f;
    const float x1 = (n0 + 1 < Nk) ? xb[1 * 64] : 0.f;
    const float x2 = (n0 + 2 < Nk) ? xb[2 * 64] : 0.f;
    const float x3 = (n0 + 3 < Nk) ? xb[3 * 64] : 0.f;
    const float x4 = (n0 + 4 < Nk) ? xb[4 * 64] : 0.f;
    const float x5 = (n0 + 5 < Nk) ? xb[5 * 64] : 0.f;
    const float x6 = (n0 + 6 < Nk) ? xb[6 * 64] : 0.f;
    const float x7 = (n0 + 7 < Nk) ? xb[7 * 64] : 0.f;

    float acc[8];
#pragma unroll
    for (int j = 0; j < 8; ++j) acc[j] = bl;

#pragma unroll
    for (int c = 0; c < 16; ++c) {
      const float4 wv = *(const float4*)(Ws + lane * WLD + c * 4);
#define KSTEP(J, XJ)                                        \
  acc[J] = fmaf(readlane_f(XJ, 4 * c + 0), wv.x, acc[J]);   \
  acc[J] = fmaf(readlane_f(XJ, 4 * c + 1), wv.y, acc[J]);   \
  acc[J] = fmaf(readlane_f(XJ, 4 * c + 2), wv.z, acc[J]);   \
  acc[J] = fmaf(readlane_f(XJ, 4 * c + 3), wv.w, acc[J]);
      KSTEP(0, x0) KSTEP(1, x1) KSTEP(2, x2) KSTEP(3, x3)
      KSTEP(4, x4) KSTEP(5, x5) KSTEP(6, x6) KSTEP(7, x7)
#undef KSTEP
    }

    // pack pairs of output dims to bf16x2, store 128B/node (32 even lanes)
#pragma unroll
    for (int j = 0; j < 8; ++j) {
      const float nb = __shfl_xor(acc[j], 1, 64);
      if (!(lane & 1) && (n0 + j) < Nk)
        Kp16[(size_t)(n0 + j) * 32 + (lane >> 1)] =
            ((unsigned int)f2bf(nb) << 16) | f2bf(acc[j]);
    }
  }
}

// ---------------------------------------------------------------------------
// bucket_scan: exclusive scan of gcnt[0..NB) -> gbase, gcursor. NB <= 1024.
// ---------------------------------------------------------------------------
__global__ __launch_bounds__(1024) void bucket_scan(
    const int* __restrict__ gcnt, int* __restrict__ gbase,
    int* __restrict__ gcursor, int NB) {
  __shared__ int wso[16];
  const int t = threadIdx.x, lane = t & 63, wv = t >> 6;
  const int v = (t < NB) ? gcnt[t] : 0;
  int x = v;
#pragma unroll
  for (int off = 1; off < 64; off <<= 1) {
    const int y = __shfl_up(x, off, 64);
    if (lane >= off) x += y;
  }
  if (lane == 63) wso[wv] = x;
  __syncthreads();
  int woff = 0;
  for (int w = 0; w < wv; ++w) woff += wso[w];
  const int excl = woff + x - v;
  if (t < NB) { gbase[t] = excl; gcursor[t] = excl; }
}

// ---------------------------------------------------------------------------
// bin_kernel: 1024 threads, 16384 edges/block: coalesced int4 reads into
// registers, LDS per-bucket count, ONE reservation atomic per bucket per
// block, (qi,ki) pairs written in ~168B contiguous runs.
// ---------------------------------------------------------------------------
__global__ __launch_bounds__(1024) void bin_kernel(
    const int* __restrict__ eq, const int* __restrict__ ek,
    int* __restrict__ gcursor, int2* __restrict__ pairs, int E, int NB) {
  __shared__ int lcnt[NBMAX];
  __shared__ int lbase[NBMAX];
  const int t = threadIdx.x;
  for (int i = t; i < NBMAX; i += 1024) lcnt[i] = 0;
  __syncthreads();

  const int cbase = blockIdx.x * CHUNK;
  int4 qv[4], kv[4];
#pragma unroll
  for (int j = 0; j < 4; ++j) {
    const int e0 = cbase + (((j << 10) + t) << 2);
    if (e0 + 3 < E) {
      qv[j] = *(const int4*)(eq + e0);
      kv[j] = *(const int4*)(ek + e0);
    } else {
      int tq[4] = {-1, -1, -1, -1}, tk[4] = {0, 0, 0, 0};
      for (int r = 0; r < 4; ++r)
        if (e0 + r < E) { tq[r] = eq[e0 + r]; tk[r] = ek[e0 + r]; }
      qv[j] = make_int4(tq[0], tq[1], tq[2], tq[3]);
      kv[j] = make_int4(tk[0], tk[1], tk[2], tk[3]);
    }
    if (qv[j].x >= 0) atomicAdd(&lcnt[qv[j].x >> BSHIFT], 1);
    if (qv[j].y >= 0) atomicAdd(&lcnt[qv[j].y >> BSHIFT], 1);
    if (qv[j].z >= 0) atomicAdd(&lcnt[qv[j].z >> BSHIFT], 1);
    if (qv[j].w >= 0) atomicAdd(&lcnt[qv[j].w >> BSHIFT], 1);
  }
  __syncthreads();
  for (int i = t; i < NB; i += 1024) {
    lbase[i] = lcnt[i] ? atomicAdd(&gcursor[i], lcnt[i]) : 0;
    lcnt[i] = 0;
  }
  __syncthreads();
#pragma unroll
  for (int j = 0; j < 4; ++j) {
    const int qs[4] = {qv[j].x, qv[j].y, qv[j].z, qv[j].w};
    const int ks[4] = {kv[j].x, kv[j].y, kv[j].z, kv[j].w};
#pragma unroll
    for (int r = 0; r < 4; ++r) {
      if (qs[r] >= 0) {
        const int b = qs[r] >> BSHIFT;
        pairs[lbase[b] + atomicAdd(&lcnt[b], 1)] = make_int2(qs[r], ks[r]);
      }
    }
  }
}

// ---------------------------------------------------------------------------
// sort_agg_kernel: one 512-thr block per 128-qi bucket (782 blocks ~3/CU).
// Phase A: register-cache the bucket's pairs, LDS counting-sort ki -> kibuf.
// Phase B (TRANSPOSED): lane = (node-sub ng 0..7, dim-group dg 0..7); each
// lane owns 8 dims of one node and walks that node's full edge list (2x
// unrolled). NO cross-lane reduction, no edge-slot padding: wsum is computed
// redundantly by the node's 8 lanes; each lane stores its own 32B directly
// (256B contiguous per node across its 8 lanes).
// ---------------------------------------------------------------------------
__global__ __launch_bounds__(512, 6) void sort_agg_kernel(
    const int2* __restrict__ pairs, const int* __restrict__ gcnt,
    const int* __restrict__ gbase, const float* __restrict__ sq,
    const float* __restrict__ sk, const float* __restrict__ ab,
    const unsigned int* __restrict__ Kp16, float* __restrict__ out,
    int Nq) {
  __shared__ int lcnt[BRANGE];
  __shared__ int lcur[BRANGE];
  __shared__ int lstart[BRANGE + 1];
  __shared__ int kibuf[KBUF_CAP];
  __shared__ int wso2[2];

  const int t = threadIdx.x;
  const int b = blockIdx.x;
  const int qlo = b << BSHIFT;
  int n = gcnt[b];
  if (n > KBUF_CAP) n = KBUF_CAP;  // statistically never; OOB guard
  const int base = gbase[b];

  if (t < BRANGE) lcnt[t] = 0;
  __syncthreads();

  // cache this thread's pairs (<= 6 at KBUF_CAP 3072)
  int2 pv[6];
  int np = 0;
#pragma unroll
  for (int r = 0; r < 6; ++r) {
    const int i = t + (r << 9);
    if (i < n) { pv[r] = pairs[base + i]; ++np; }
  }
#pragma unroll
  for (int r = 0; r < 6; ++r)
    if (r < np) atomicAdd(&lcnt[pv[r].x - qlo], 1);
  __syncthreads();

  // exclusive scan of lcnt[0..127] (first 2 waves)
  const int lane = t & 63, wv = t >> 6;
  int v = 0, x = 0;
  if (t < BRANGE) {
    v = lcnt[t];
    x = v;
#pragma unroll
    for (int off = 1; off < 64; off <<= 1) {
      const int y = __shfl_up(x, off, 64);
      if (lane >= off) x += y;
    }
    if (lane == 63) wso2[wv] = x;
  }
  __syncthreads();
  if (t < BRANGE) {
    const int excl = ((wv == 1) ? wso2[0] : 0) + x - v;
    lstart[t] = excl;
    lcur[t] = excl;
    if (t == BRANGE - 1) lstart[BRANGE] = excl + v;
  }
  __syncthreads();

  // scatter ki into kibuf (sorted by local qi)
#pragma unroll
  for (int r = 0; r < 6; ++r)
    if (r < np) kibuf[atomicAdd(&lcur[pv[r].x - qlo], 1)] = pv[r].y;
  __syncthreads();

  // Phase B: transposed aggregation. 8 waves x 8 nodes = 64 nodes per pass.
  const int ng = lane >> 3, dg = lane & 7;
  const float abv = ab[0];
#pragma unroll
  for (int pass = 0; pass < 2; ++pass) {
    const int l = (pass << 6) + (wv << 3) + ng;
    const int node = qlo + l;
    const bool act = node < Nq;
    const int s = act ? lstart[l] : 0;
    const int e = act ? lstart[l + 1] : 0;
    const float sqn = act ? sq[node] + abv : 0.f;

    float acc[8] = {0.f, 0.f, 0.f, 0.f, 0.f, 0.f, 0.f, 0.f};
    float wsum = 0.f;
    int j = s;
    for (; j + 1 < e; j += 2) {
      const int k1 = kibuf[j];
      const int k2 = kibuf[j + 1];
      float x1 = sqn + sk[k1];
      float x2 = sqn + sk[k2];
      x1 = x1 > 0.f ? x1 : ALPHA_LEAKY * x1;
      x2 = x2 > 0.f ? x2 : ALPHA_LEAKY * x2;
      const float w1 = __expf(x1);
      const float w2 = __expf(x2);
      const uint4 u1 = *(const uint4*)(Kp16 + (size_t)k1 * 32 + (dg << 2));
      const uint4 u2 = *(const uint4*)(Kp16 + (size_t)k2 * 32 + (dg << 2));
      acc[0] = fmaf(w1, __uint_as_float(u1.x << 16), acc[0]);
      acc[1] = fmaf(w1, __uint_as_float(u1.x & 0xffff0000u), acc[1]);
      acc[2] = fmaf(w1, __uint_as_float(u1.y << 16), acc[2]);
      acc[3] = fmaf(w1, __uint_as_float(u1.y & 0xffff0000u), acc[3]);
      acc[4] = fmaf(w1, __uint_as_float(u1.z << 16), acc[4]);
      acc[5] = fmaf(w1, __uint_as_float(u1.z & 0xffff0000u), acc[5]);
      acc[6] = fmaf(w1, __uint_as_float(u1.w << 16), acc[6]);
      acc[7] = fmaf(w1, __uint_as_float(u1.w & 0xffff0000u), acc[7]);
      acc[0] = fmaf(w2, __uint_as_float(u2.x << 16), acc[0]);
      acc[1] = fmaf(w2, __uint_as_float(u2.x & 0xffff0000u), acc[1]);
      acc[2] = fmaf(w2, __uint_as_float(u2.y << 16), acc[2]);
      acc[3] = fmaf(w2, __uint_as_float(u2.y & 0xffff0000u), acc[3]);
      acc[4] = fmaf(w2, __uint_as_float(u2.z << 16), acc[4]);
      acc[5] = fmaf(w2, __uint_as_float(u2.z & 0xffff0000u), acc[5]);
      acc[6] = fmaf(w2, __uint_as_float(u2.w << 16), acc[6]);
      acc[7] = fmaf(w2, __uint_as_float(u2.w & 0xffff0000u), acc[7]);
      wsum += w1 + w2;
    }
    if (j < e) {
      const int k1 = kibuf[j];
      float x1 = sqn + sk[k1];
      x1 = x1 > 0.f ? x1 : ALPHA_LEAKY * x1;
      const float w1 = __expf(x1);
      const uint4 u1 = *(const uint4*)(Kp16 + (size_t)k1 * 32 + (dg << 2));
      acc[0] = fmaf(w1, __uint_as_float(u1.x << 16), acc[0]);
      acc[1] = fmaf(w1, __uint_as_float(u1.x & 0xffff0000u), acc[1]);
      acc[2] = fmaf(w1, __uint_as_float(u1.y << 16), acc[2]);
      acc[3] = fmaf(w1, __uint_as_float(u1.y & 0xffff0000u), acc[3]);
      acc[4] = fmaf(w1, __uint_as_float(u1.z << 16), acc[4]);
      acc[5] = fmaf(w1, __uint_as_float(u1.z & 0xffff0000u), acc[5]);
      acc[6] = fmaf(w1, __uint_as_float(u1.w << 16), acc[6]);
      acc[7] = fmaf(w1, __uint_as_float(u1.w & 0xffff0000u), acc[7]);
      wsum += w1;
    }
    if (act) {
      const float inv = 1.0f / (wsum + EPS_F);
      float4 r0 = {acc[0] * inv, acc[1] * inv, acc[2] * inv, acc[3] * inv};
      float4 r1 = {acc[4] * inv, acc[5] * inv, acc[6] * inv, acc[7] * inv};
      float* o = out + (size_t)node * 64 + (dg << 3);
      *(float4*)o = r0;
      *(float4*)(o + 4) = r1;
    }
  }
}

extern "C" void kernel_launch(void* const* d_in, const int* in_sizes, int n_in,
                              void* d_out, int out_size, void* d_ws, size_t ws_size,
                              hipStream_t stream) {
  const float* qnodes = (const float*)d_in[0];   // (Nq, 64) f32
  const float* kvnodes = (const float*)d_in[1];  // (Nk, 64) f32
  const int* ei = (const int*)d_in[2];           // (2, E) int32
  const float* W = (const float*)d_in[3];        // (64, 64)
  const float* pb = (const float*)d_in[4];       // (64,)
  const float* aw = (const float*)d_in[5];       // (1, 128): [wq | wk]
  const float* ab = (const float*)d_in[6];       // (1,)

  const int Nq = in_sizes[0] / 64;
  const int Nk = in_sizes[1] / 64;
  const int E = in_sizes[2] / 2;
  const int NB = (Nq + BRANGE - 1) >> BSHIFT;    // 782 at Nq=100000

  const int* eq = ei;
  const int* ek = ei + E;

  // --- workspace layout ---
  char* ws = (char*)d_ws;
  int2* pairs = (int2*)ws;                              // E int2
  unsigned int* Kp16 = (unsigned int*)(pairs + E);      // Nk*32 words
  float* sq = (float*)(Kp16 + (size_t)Nk * 32);         // Nq
  float* sk = sq + Nq;                                  // Nk
  int* gcnt = (int*)(sk + Nk);                          // NBMAX
  int* gbase = gcnt + NBMAX;                            // NBMAX
  int* gcursor = gbase + NBMAX;                         // NBMAX

  hipMemsetAsync(gcnt, 0, NBMAX * sizeof(int), stream);

  // --- hist + projections (independent; fused into one launch) ---
  const int projBlocks = 1536;
  hist_proj_kernel<<<HIST_BLOCKS + projBlocks, 256, 0, stream>>>(
      eq, gcnt, E, NB, qnodes, kvnodes, W, pb, aw, Kp16, sq, sk, Nq, Nk,
      projBlocks);

  // --- scan + binning ---
  bucket_scan<<<1, 1024, 0, stream>>>(gcnt, gbase, gcursor, NB);
  bin_kernel<<<(E + CHUNK - 1) / CHUNK, 1024, 0, stream>>>(eq, ek, gcursor,
                                                           pairs, E, NB);

  // --- fused bucket sort + transposed aggregation ---
  sort_agg_kernel<<<NB, 512, 0, stream>>>(pairs, gcnt, gbase, sq, sk, ab,
                                          Kp16, (float*)d_out, Nq);
}